// Round 3
// baseline (893.247 us; speedup 1.0000x reference)
//
#include <hip/hip_runtime.h>

typedef __bf16 bf16;
typedef __bf16 bf16x4 __attribute__((ext_vector_type(4)));
typedef __bf16 bf16x8 __attribute__((ext_vector_type(8)));
typedef float f32x4 __attribute__((ext_vector_type(4)));
typedef float f32x16 __attribute__((ext_vector_type(16)));
typedef int i32x2 __attribute__((ext_vector_type(2)));
typedef unsigned int u32;

#define DIMC 384
#define NHEADS 12
#define NTOK 49
#define NWINB 4096
#define MROWS (NWINB*NTOK)   // 200704

#define MFMA32(A,B,C) __builtin_amdgcn_mfma_f32_32x32x16_bf16(A,B,C,0,0,0)

// async global->LDS, 16B per lane; LDS dest is wave-uniform base + lane*16
#define GLOAD16(gsrc, lbase) \
  __builtin_amdgcn_global_load_lds( \
      (const __attribute__((address_space(1))) u32*)(gsrc), \
      (__attribute__((address_space(3))) u32*)(lbase), 16, 0, 0)

// ---------------- convert f32 -> bf16 (vectorized) ----------------
__global__ __launch_bounds__(256) void k_convert(const float4* __restrict__ in,
                                                 bf16x4* __restrict__ out, int n4) {
  int stride = gridDim.x * blockDim.x;
  for (int i = blockIdx.x * blockDim.x + threadIdx.x; i < n4; i += stride) {
    float4 v = in[i];
    bf16x4 o;
    o[0] = (bf16)v.x; o[1] = (bf16)v.y; o[2] = (bf16)v.z; o[3] = (bf16)v.w;
    out[i] = o;
  }
}

// ---------------- transposed bias: biasT[h][key][q] = table[rel[q*49+key]*12 + h] ----------------
__global__ __launch_bounds__(256) void k_biasT(const float* __restrict__ table,
                                               const int* __restrict__ rel,
                                               float* __restrict__ outp) {
  int i = blockIdx.x * 256 + threadIdx.x;
  if (i < NHEADS * NTOK * NTOK) {
    int h = i / (NTOK * NTOK), r2 = i - h * (NTOK * NTOK);
    int key = r2 / NTOK, q = r2 - key * NTOK;
    outp[i] = table[rel[q * NTOK + key] * NHEADS + h];
  }
}

// ---------------- transposed mask: maskT[w][key][q] = mask[w][q][key] ----------------
__global__ __launch_bounds__(256) void k_maskT(const float* __restrict__ mask,
                                               float* __restrict__ outp) {
  int i = blockIdx.x * 256 + threadIdx.x;
  if (i < 64 * NTOK * NTOK) {
    int w = i / (NTOK * NTOK), r2 = i - w * (NTOK * NTOK);
    int key = r2 / NTOK, q = r2 - key * NTOK;
    outp[i] = mask[(w * NTOK + q) * NTOK + key];
  }
}

// ---------------- GEMM: C = A(M,K) * Bw(N,K)^T, bf16 in, f32 acc ----------------
// Linear LDS [128][64] + XOR swizzle (byte col ^= (row&7)<<4), staged via
// global_load_lds w=16 with pre-swizzled per-lane GLOBAL source (rule #21:
// both-sides-or-neither). Grid: x = N-blocks (fast), y = M-blocks, so the
// small B operand stays L2-resident and A is fetched ~once.
// MODE 0: QKV (N=1152), scatter q/k/v bf16.  MODE 1: proj (N=384), f32 out + bias.
template <int MODE>
__global__ __launch_bounds__(256) void k_gemm(const bf16* __restrict__ A,
                                              const bf16* __restrict__ Bw,
                                              const float* __restrict__ bias,
                                              bf16* __restrict__ oQ, bf16* __restrict__ oK,
                                              bf16* __restrict__ oV, float* __restrict__ oP) {
  __shared__ __align__(16) bf16 lA[128 * 64];
  __shared__ __align__(16) bf16 lB[128 * 64];
  const int t = threadIdx.x;
  const int l = t & 63;
  const int wv = t >> 6;
  const int wr = wv >> 1, wc = wv & 1;   // 2x2 waves, 64x64 each
  const int n0 = blockIdx.x * 128;
  const int m0 = blockIdx.y * 128;
  const int lr = l & 15, lg = l >> 4;

  // staging geometry: lane's linear tile byte offset = wv*4096 + i*1024 + l*16
  const int srow = wv * 32 + (l >> 3);           // + i*8 per issue
  const int scolb = (l & 7) * 16;                // byte col within 128B row

  f32x4 acc[4][4] = {};

  for (int k0 = 0; k0 < DIMC; k0 += 64) {
    __syncthreads();
#pragma unroll
    for (int i = 0; i < 4; ++i) {
      int row = srow + i * 8;
      int scol = (scolb ^ ((row & 7) << 4)) >> 1;   // pre-swizzled source col (elems)
      GLOAD16(&A[(size_t)(m0 + row) * DIMC + k0 + scol], &lA[wv * 2048 + i * 512]);
      GLOAD16(&Bw[(size_t)(n0 + row) * DIMC + k0 + scol], &lB[wv * 2048 + i * 512]);
    }
    __syncthreads();
#pragma unroll
    for (int kk = 0; kk < 64; kk += 32) {
      bf16x8 af[4], bfv[4];
#pragma unroll
      for (int f = 0; f < 4; ++f) {
        int row = wr * 64 + f * 16 + lr;
        int cb = (kk + lg * 8) * 2;
        af[f] = *reinterpret_cast<const bf16x8*>(
            &lA[row * 64 + ((cb ^ ((row & 7) << 4)) >> 1)]);
      }
#pragma unroll
      for (int f = 0; f < 4; ++f) {
        int row = wc * 64 + f * 16 + lr;
        int cb = (kk + lg * 8) * 2;
        bfv[f] = *reinterpret_cast<const bf16x8*>(
            &lB[row * 64 + ((cb ^ ((row & 7) << 4)) >> 1)]);
      }
#pragma unroll
      for (int fm = 0; fm < 4; ++fm)
#pragma unroll
        for (int fn = 0; fn < 4; ++fn)
          acc[fm][fn] = __builtin_amdgcn_mfma_f32_16x16x32_bf16(af[fm], bfv[fn], acc[fm][fn], 0, 0, 0);
    }
  }

  // epilogue: C/D frag mapping col = lane&15, row = (lane>>4)*4 + r  [m89-verified]
#pragma unroll
  for (int fm = 0; fm < 4; ++fm) {
#pragma unroll
    for (int fn = 0; fn < 4; ++fn) {
      int c = n0 + wc * 64 + fn * 16 + lr;
      float bc = bias[c];
#pragma unroll
      for (int r = 0; r < 4; ++r) {
        int m = m0 + wr * 64 + fm * 16 + lg * 4 + r;
        float v = acc[fm][fn][r] + bc;
        if (MODE == 0) {
          int b = m / 49, n = m - b * 49;
          int which = c / 384;
          int rem = c - which * 384;
          int h = rem >> 5, d = rem & 31;
          bf16* dst = which == 0 ? oQ : (which == 1 ? oK : oV);
          dst[((b * 12 + h) * 49 + n) * 32 + d] = (bf16)v;
        } else {
          oP[m * 384 + c] = v;
        }
      }
    }
  }
}

// ---------------- fused window attention: one wave per (b,h), 32x32 MFMA ----------------
__global__ __launch_bounds__(256, 4) void k_attn(const bf16* __restrict__ Q,
                                                 const bf16* __restrict__ K,
                                                 const bf16* __restrict__ V,
                                                 const float* __restrict__ biasT,
                                                 const float* __restrict__ maskT,
                                                 bf16* __restrict__ H) {
  __shared__ __align__(16) bf16 Vl[4][32 * 72];
  const int t = threadIdx.x, l = t & 63, wv = t >> 6;
  const int p = blockIdx.x * 4 + wv;   // b*12 + h
  const int b = p / 12, h = p - b * 12;
  const int w = b & 63;
  const size_t base = (size_t)p * (49 * 32);
  const int c = l & 31, b5 = l >> 5;
  bf16* vl = Vl[wv];

  {
    bf16x4 z = {};
    for (int i = l; i < 128; i += 64) {
      int d = i >> 2, kq = 48 + (i & 3) * 4;
      *reinterpret_cast<bf16x4*>(&vl[d * 72 + kq]) = z;
    }
  }
  for (int i = l; i < 392; i += 64) {
    int key = i >> 3, dc = (i & 7) * 4;
    bf16x4 vv = *reinterpret_cast<const bf16x4*>(&V[base + key * 32 + dc]);
#pragma unroll
    for (int j = 0; j < 4; ++j) vl[(dc + j) * 72 + key] = vv[j];
  }

  bf16x8 kf[2][2], qf[2][2];
#pragma unroll
  for (int f = 0; f < 2; ++f) {
    int row = f * 32 + c; if (row > 48) row = 48;
#pragma unroll
    for (int kd = 0; kd < 2; ++kd) {
      kf[f][kd] = *reinterpret_cast<const bf16x8*>(&K[base + row * 32 + kd * 16 + b5 * 8]);
      qf[f][kd] = *reinterpret_cast<const bf16x8*>(&Q[base + row * 32 + kd * 16 + b5 * 8]);
    }
  }

  const float scale = 0.17677669529663689f;   // 32^-0.5
  const float* bT = biasT + h * 2401;
  const float* mT = maskT + w * 2401;

#pragma unroll
  for (int fn = 0; fn < 2; ++fn) {
    f32x16 s0 = {}, s1 = {};
    s0 = MFMA32(kf[0][0], qf[fn][0], s0);
    s0 = MFMA32(kf[0][1], qf[fn][1], s0);
    s1 = MFMA32(kf[1][0], qf[fn][0], s1);
    s1 = MFMA32(kf[1][1], qf[fn][1], s1);

    int q = fn * 32 + c;
    int qc = q > 48 ? 48 : q;

    float vals[32];
    float vmax = -1e30f;
#pragma unroll
    for (int fm = 0; fm < 2; ++fm) {
#pragma unroll
      for (int r = 0; r < 16; ++r) {
        int key = fm * 32 + (r & 3) + 8 * (r >> 2) + 4 * b5;
        float sv = fm ? s1[r] : s0[r];
        float v;
        if (key < 49) {
          float cm = bT[key * 49 + qc] + mT[key * 49 + qc];
          v = fmaf(sv, scale, cm);
        } else {
          v = -1e30f;
        }
        vals[fm * 16 + r] = v;
        vmax = fmaxf(vmax, v);
      }
    }
    vmax = fmaxf(vmax, __shfl_xor(vmax, 32));
    float sum = 0.f;
#pragma unroll
    for (int i = 0; i < 32; ++i) {
      float e = __expf(vals[i] - vmax);
      vals[i] = e;
      sum += e;
    }
    sum += __shfl_xor(sum, 32);
    float inv = 1.f / sum;

    f32x16 o = {};
#pragma unroll
    for (int kk = 0; kk < 4; ++kk) {
      int ib = (kk >> 1) * 16 + 8 * (kk & 1);
      union { bf16 hh[2]; u32 u; } cv;
      u32 A0, A1, B0, B1;
      cv.hh[0] = (bf16)(vals[ib + 0] * inv); cv.hh[1] = (bf16)(vals[ib + 1] * inv); A0 = cv.u;
      cv.hh[0] = (bf16)(vals[ib + 2] * inv); cv.hh[1] = (bf16)(vals[ib + 3] * inv); A1 = cv.u;
      cv.hh[0] = (bf16)(vals[ib + 4] * inv); cv.hh[1] = (bf16)(vals[ib + 5] * inv); B0 = cv.u;
      cv.hh[0] = (bf16)(vals[ib + 6] * inv); cv.hh[1] = (bf16)(vals[ib + 7] * inv); B1 = cv.u;
      i32x2 sw0 = __builtin_amdgcn_permlane32_swap((int)A0, (int)B0, false, false);
      i32x2 sw1 = __builtin_amdgcn_permlane32_swap((int)A1, (int)B1, false, false);
      union { u32 d[4]; bf16x8 v8; } pa;
      pa.d[0] = (u32)sw0[0]; pa.d[1] = (u32)sw1[0];
      pa.d[2] = (u32)sw0[1]; pa.d[3] = (u32)sw1[1];
      bf16x8 vf = *reinterpret_cast<const bf16x8*>(&vl[c * 72 + kk * 16 + b5 * 8]);
      o = MFMA32(pa.v8, vf, o);
    }

#pragma unroll
    for (int r = 0; r < 16; ++r) {
      int qrow = fn * 32 + (r & 3) + 8 * (r >> 2) + 4 * b5;
      if (qrow < 49)
        H[((size_t)b * 49 + qrow) * 384 + h * 32 + c] = (bf16)o[r];
    }
  }
}

extern "C" void kernel_launch(void* const* d_in, const int* in_sizes, int n_in,
                              void* d_out, int out_size, void* d_ws, size_t ws_size,
                              hipStream_t stream) {
  const float* x     = (const float*)d_in[0];
  const float* mask  = (const float*)d_in[1];
  const float* qkvw  = (const float*)d_in[2];
  const float* qkvb  = (const float*)d_in[3];
  const float* btab  = (const float*)d_in[4];
  const float* projw = (const float*)d_in[5];
  const float* projb = (const float*)d_in[6];
  const int*   rel   = (const int*)d_in[7];
  float* out = (float*)d_out;

  const size_t NELEM = (size_t)MROWS * DIMC;  // 77,070,336
  char* ws = (char*)d_ws;
  // ws layout (bytes):
  //   xb/hidden [0, 154140672)
  //   v         [154140672, 308281344)
  //   biasT     [308281344, +115456)
  //   wqkv      [308396800, +884736)   <- maskT (614656 B) reuses this AFTER gemm0
  //   wproj     [309281536, +294912)
  bf16*  xb    = (bf16*)ws;
  bf16*  vb    = (bf16*)(ws + 154140672);
  float* biasT = (float*)(ws + 308281344);
  bf16*  wqkv  = (bf16*)(ws + 308396800);
  float* maskT = (float*)(ws + 308396800);   // aliases wqkv; written after gemm0
  bf16*  wproj = (bf16*)(ws + 309281536);
  // q,k live in d_out as scratch (exactly 2 * 154,140,672 B); proj fully overwrites it
  bf16* qb = (bf16*)d_out;
  bf16* kb = qb + NELEM;

  k_convert<<<2048, 256, 0, stream>>>((const float4*)x, (bf16x4*)xb, (int)(NELEM / 4));
  k_convert<<<432, 256, 0, stream>>>((const float4*)qkvw, (bf16x4*)wqkv, 3 * DIMC * DIMC / 4);
  k_convert<<<144, 256, 0, stream>>>((const float4*)projw, (bf16x4*)wproj, DIMC * DIMC / 4);
  k_biasT<<<(NHEADS * NTOK * NTOK + 255) / 256, 256, 0, stream>>>(btab, rel, biasT);

  k_gemm<0><<<dim3(1152 / 128, MROWS / 128), 256, 0, stream>>>(xb, wqkv, qkvb, qb, kb, vb, nullptr);
  k_maskT<<<(64 * NTOK * NTOK + 255) / 256, 256, 0, stream>>>(mask, maskT);
  k_attn<<<(NWINB * NHEADS) / 4, 256, 0, stream>>>(qb, kb, vb, biasT, maskT, xb);
  k_gemm<1><<<dim3(384 / 128, MROWS / 128), 256, 0, stream>>>(xb, wproj, projb, nullptr, nullptr, nullptr, out);
}

// Round 4
// 865.773 us; speedup vs baseline: 1.0317x; 1.0317x over previous
//
#include <hip/hip_runtime.h>

typedef __bf16 bf16;
typedef __bf16 bf16x4 __attribute__((ext_vector_type(4)));
typedef __bf16 bf16x8 __attribute__((ext_vector_type(8)));
typedef float f32x4 __attribute__((ext_vector_type(4)));
typedef float f32x16 __attribute__((ext_vector_type(16)));
typedef int i32x2 __attribute__((ext_vector_type(2)));
typedef unsigned int u32;

#define DIMC 384
#define NHEADS 12
#define NTOK 49
#define NWINB 4096
#define MROWS (NWINB*NTOK)   // 200704

#define MFMA32(A,B,C) __builtin_amdgcn_mfma_f32_32x32x16_bf16(A,B,C,0,0,0)

// async global->LDS, 16B per lane; LDS dest is wave-uniform base + lane*16
#define GLOAD16(gsrc, lbase) \
  __builtin_amdgcn_global_load_lds( \
      (const __attribute__((address_space(1))) u32*)(gsrc), \
      (__attribute__((address_space(3))) u32*)(lbase), 16, 0, 0)

// ---------------- convert f32 -> bf16 (vectorized) ----------------
__global__ __launch_bounds__(256) void k_convert(const float4* __restrict__ in,
                                                 bf16x4* __restrict__ out, int n4) {
  int stride = gridDim.x * blockDim.x;
  for (int i = blockIdx.x * blockDim.x + threadIdx.x; i < n4; i += stride) {
    float4 v = in[i];
    bf16x4 o;
    o[0] = (bf16)v.x; o[1] = (bf16)v.y; o[2] = (bf16)v.z; o[3] = (bf16)v.w;
    out[i] = o;
  }
}

// ---------------- transposed bias: biasT[h][key][q] = table[rel[q*49+key]*12 + h] ----------------
__global__ __launch_bounds__(256) void k_biasT(const float* __restrict__ table,
                                               const int* __restrict__ rel,
                                               float* __restrict__ outp) {
  int i = blockIdx.x * 256 + threadIdx.x;
  if (i < NHEADS * NTOK * NTOK) {
    int h = i / (NTOK * NTOK), r2 = i - h * (NTOK * NTOK);
    int key = r2 / NTOK, q = r2 - key * NTOK;
    outp[i] = table[rel[q * NTOK + key] * NHEADS + h];
  }
}

// ---------------- transposed mask: maskT[w][key][q] = mask[w][q][key] ----------------
__global__ __launch_bounds__(256) void k_maskT(const float* __restrict__ mask,
                                               float* __restrict__ outp) {
  int i = blockIdx.x * 256 + threadIdx.x;
  if (i < 64 * NTOK * NTOK) {
    int w = i / (NTOK * NTOK), r2 = i - w * (NTOK * NTOK);
    int key = r2 / NTOK, q = r2 - key * NTOK;
    outp[i] = mask[(w * NTOK + q) * NTOK + key];
  }
}

// ---------------- GEMM: C = A(M,K) * Bw(N,K)^T, bf16 in, f32 acc ----------------
// Linear LDS [128][64] + XOR swizzle via pre-swizzled global source (rule #21),
// staged with global_load_lds w=16.
// XCD-chunk remap (T1, y-major): each XCD owns nwg/8 consecutive logical blocks
// = a contiguous range of M-panels, iterating all N-blocks per panel. A-panels
// are then fetched by exactly one XCD exactly once; B stays L2-resident.
// MODE 0: QKV (N=1152), scatter q/k/v bf16.  MODE 1: proj (N=384), f32 out + bias.
template <int MODE>
__global__ __launch_bounds__(256) void k_gemm(const bf16* __restrict__ A,
                                              const bf16* __restrict__ Bw,
                                              const float* __restrict__ bias,
                                              bf16* __restrict__ oQ, bf16* __restrict__ oK,
                                              bf16* __restrict__ oV, float* __restrict__ oP) {
  __shared__ __align__(16) bf16 lA[128 * 64];
  __shared__ __align__(16) bf16 lB[128 * 64];
  const int t = threadIdx.x;
  const int l = t & 63;
  const int wv = t >> 6;
  const int wr = wv >> 1, wc = wv & 1;   // 2x2 waves, 64x64 each

  // ---- bijective XCD-chunk remap (nwg % 8 == 0 for both modes) ----
  const u32 NXB = MODE == 0 ? 9 : 3;                 // N-blocks
  const u32 nwg = NXB * (MROWS / 128);
  u32 lin = blockIdx.y * gridDim.x + blockIdx.x;     // dispatch-linear (x fastest)
  u32 logical = (lin & 7) * (nwg >> 3) + (lin >> 3); // XCD gets contiguous chunk
  const int n0 = (int)(logical % NXB) * 128;
  const int m0 = (int)(logical / NXB) * 128;

  const int lr = l & 15, lg = l >> 4;

  // staging geometry: lane's linear tile byte offset = wv*4096 + i*1024 + l*16
  const int srow = wv * 32 + (l >> 3);           // + i*8 per issue
  const int scolb = (l & 7) * 16;                // byte col within 128B row

  f32x4 acc[4][4] = {};

  for (int k0 = 0; k0 < DIMC; k0 += 64) {
    __syncthreads();
#pragma unroll
    for (int i = 0; i < 4; ++i) {
      int row = srow + i * 8;
      int scol = (scolb ^ ((row & 7) << 4)) >> 1;   // pre-swizzled source col (elems)
      GLOAD16(&A[(size_t)(m0 + row) * DIMC + k0 + scol], &lA[wv * 2048 + i * 512]);
      GLOAD16(&Bw[(size_t)(n0 + row) * DIMC + k0 + scol], &lB[wv * 2048 + i * 512]);
    }
    __syncthreads();
#pragma unroll
    for (int kk = 0; kk < 64; kk += 32) {
      bf16x8 af[4], bfv[4];
#pragma unroll
      for (int f = 0; f < 4; ++f) {
        int row = wr * 64 + f * 16 + lr;
        int cb = (kk + lg * 8) * 2;
        af[f] = *reinterpret_cast<const bf16x8*>(
            &lA[row * 64 + ((cb ^ ((row & 7) << 4)) >> 1)]);
      }
#pragma unroll
      for (int f = 0; f < 4; ++f) {
        int row = wc * 64 + f * 16 + lr;
        int cb = (kk + lg * 8) * 2;
        bfv[f] = *reinterpret_cast<const bf16x8*>(
            &lB[row * 64 + ((cb ^ ((row & 7) << 4)) >> 1)]);
      }
#pragma unroll
      for (int fm = 0; fm < 4; ++fm)
#pragma unroll
        for (int fn = 0; fn < 4; ++fn)
          acc[fm][fn] = __builtin_amdgcn_mfma_f32_16x16x32_bf16(af[fm], bfv[fn], acc[fm][fn], 0, 0, 0);
    }
  }

  // epilogue: C/D frag mapping col = lane&15, row = (lane>>4)*4 + r  [m89-verified]
#pragma unroll
  for (int fm = 0; fm < 4; ++fm) {
#pragma unroll
    for (int fn = 0; fn < 4; ++fn) {
      int c = n0 + wc * 64 + fn * 16 + lr;
      float bc = bias[c];
#pragma unroll
      for (int r = 0; r < 4; ++r) {
        int m = m0 + wr * 64 + fm * 16 + lg * 4 + r;
        float v = acc[fm][fn][r] + bc;
        if (MODE == 0) {
          int b = m / 49, n = m - b * 49;
          int which = c / 384;
          int rem = c - which * 384;
          int h = rem >> 5, d = rem & 31;
          bf16* dst = which == 0 ? oQ : (which == 1 ? oK : oV);
          dst[((b * 12 + h) * 49 + n) * 32 + d] = (bf16)v;
        } else {
          oP[m * 384 + c] = v;
        }
      }
    }
  }
}

// ---------------- fused window attention: one wave per (b,h), 32x32 MFMA ----------------
__global__ __launch_bounds__(256, 4) void k_attn(const bf16* __restrict__ Q,
                                                 const bf16* __restrict__ K,
                                                 const bf16* __restrict__ V,
                                                 const float* __restrict__ biasT,
                                                 const float* __restrict__ maskT,
                                                 bf16* __restrict__ H) {
  __shared__ __align__(16) bf16 Vl[4][32 * 72];
  const int t = threadIdx.x, l = t & 63, wv = t >> 6;
  const int p = blockIdx.x * 4 + wv;   // b*12 + h
  const int b = p / 12, h = p - b * 12;
  const int w = b & 63;
  const size_t base = (size_t)p * (49 * 32);
  const int c = l & 31, b5 = l >> 5;
  bf16* vl = Vl[wv];

  {
    bf16x4 z = {};
    for (int i = l; i < 128; i += 64) {
      int d = i >> 2, kq = 48 + (i & 3) * 4;
      *reinterpret_cast<bf16x4*>(&vl[d * 72 + kq]) = z;
    }
  }
  for (int i = l; i < 392; i += 64) {
    int key = i >> 3, dc = (i & 7) * 4;
    bf16x4 vv = *reinterpret_cast<const bf16x4*>(&V[base + key * 32 + dc]);
#pragma unroll
    for (int j = 0; j < 4; ++j) vl[(dc + j) * 72 + key] = vv[j];
  }

  bf16x8 kf[2][2], qf[2][2];
#pragma unroll
  for (int f = 0; f < 2; ++f) {
    int row = f * 32 + c; if (row > 48) row = 48;
#pragma unroll
    for (int kd = 0; kd < 2; ++kd) {
      kf[f][kd] = *reinterpret_cast<const bf16x8*>(&K[base + row * 32 + kd * 16 + b5 * 8]);
      qf[f][kd] = *reinterpret_cast<const bf16x8*>(&Q[base + row * 32 + kd * 16 + b5 * 8]);
    }
  }

  const float scale = 0.17677669529663689f;   // 32^-0.5
  const float* bT = biasT + h * 2401;
  const float* mT = maskT + w * 2401;

#pragma unroll
  for (int fn = 0; fn < 2; ++fn) {
    f32x16 s0 = {}, s1 = {};
    s0 = MFMA32(kf[0][0], qf[fn][0], s0);
    s0 = MFMA32(kf[0][1], qf[fn][1], s0);
    s1 = MFMA32(kf[1][0], qf[fn][0], s1);
    s1 = MFMA32(kf[1][1], qf[fn][1], s1);

    int q = fn * 32 + c;
    int qc = q > 48 ? 48 : q;

    float vals[32];
    float vmax = -1e30f;
#pragma unroll
    for (int fm = 0; fm < 2; ++fm) {
#pragma unroll
      for (int r = 0; r < 16; ++r) {
        int key = fm * 32 + (r & 3) + 8 * (r >> 2) + 4 * b5;
        float sv = fm ? s1[r] : s0[r];
        float v;
        if (key < 49) {
          float cm = bT[key * 49 + qc] + mT[key * 49 + qc];
          v = fmaf(sv, scale, cm);
        } else {
          v = -1e30f;
        }
        vals[fm * 16 + r] = v;
        vmax = fmaxf(vmax, v);
      }
    }
    vmax = fmaxf(vmax, __shfl_xor(vmax, 32));
    float sum = 0.f;
#pragma unroll
    for (int i = 0; i < 32; ++i) {
      float e = __expf(vals[i] - vmax);
      vals[i] = e;
      sum += e;
    }
    sum += __shfl_xor(sum, 32);
    float inv = 1.f / sum;

    f32x16 o = {};
#pragma unroll
    for (int kk = 0; kk < 4; ++kk) {
      int ib = (kk >> 1) * 16 + 8 * (kk & 1);
      union { bf16 hh[2]; u32 u; } cv;
      u32 A0, A1, B0, B1;
      cv.hh[0] = (bf16)(vals[ib + 0] * inv); cv.hh[1] = (bf16)(vals[ib + 1] * inv); A0 = cv.u;
      cv.hh[0] = (bf16)(vals[ib + 2] * inv); cv.hh[1] = (bf16)(vals[ib + 3] * inv); A1 = cv.u;
      cv.hh[0] = (bf16)(vals[ib + 4] * inv); cv.hh[1] = (bf16)(vals[ib + 5] * inv); B0 = cv.u;
      cv.hh[0] = (bf16)(vals[ib + 6] * inv); cv.hh[1] = (bf16)(vals[ib + 7] * inv); B1 = cv.u;
      i32x2 sw0 = __builtin_amdgcn_permlane32_swap((int)A0, (int)B0, false, false);
      i32x2 sw1 = __builtin_amdgcn_permlane32_swap((int)A1, (int)B1, false, false);
      union { u32 d[4]; bf16x8 v8; } pa;
      pa.d[0] = (u32)sw0[0]; pa.d[1] = (u32)sw1[0];
      pa.d[2] = (u32)sw0[1]; pa.d[3] = (u32)sw1[1];
      bf16x8 vf = *reinterpret_cast<const bf16x8*>(&vl[c * 72 + kk * 16 + b5 * 8]);
      o = MFMA32(pa.v8, vf, o);
    }

#pragma unroll
    for (int r = 0; r < 16; ++r) {
      int qrow = fn * 32 + (r & 3) + 8 * (r >> 2) + 4 * b5;
      if (qrow < 49)
        H[((size_t)b * 49 + qrow) * 384 + h * 32 + c] = (bf16)o[r];
    }
  }
}

extern "C" void kernel_launch(void* const* d_in, const int* in_sizes, int n_in,
                              void* d_out, int out_size, void* d_ws, size_t ws_size,
                              hipStream_t stream) {
  const float* x     = (const float*)d_in[0];
  const float* mask  = (const float*)d_in[1];
  const float* qkvw  = (const float*)d_in[2];
  const float* qkvb  = (const float*)d_in[3];
  const float* btab  = (const float*)d_in[4];
  const float* projw = (const float*)d_in[5];
  const float* projb = (const float*)d_in[6];
  const int*   rel   = (const int*)d_in[7];
  float* out = (float*)d_out;

  const size_t NELEM = (size_t)MROWS * DIMC;  // 77,070,336
  char* ws = (char*)d_ws;
  // ws layout (bytes):
  //   xb/hidden [0, 154140672)
  //   v         [154140672, 308281344)
  //   biasT     [308281344, +115456)
  //   wqkv      [308396800, +884736)   <- maskT (614656 B) reuses this AFTER gemm0
  //   wproj     [309281536, +294912)
  bf16*  xb    = (bf16*)ws;
  bf16*  vb    = (bf16*)(ws + 154140672);
  float* biasT = (float*)(ws + 308281344);
  bf16*  wqkv  = (bf16*)(ws + 308396800);
  float* maskT = (float*)(ws + 308396800);   // aliases wqkv; written after gemm0
  bf16*  wproj = (bf16*)(ws + 309281536);
  // q,k live in d_out as scratch (exactly 2 * 154,140,672 B); proj fully overwrites it
  bf16* qb = (bf16*)d_out;
  bf16* kb = qb + NELEM;

  k_convert<<<2048, 256, 0, stream>>>((const float4*)x, (bf16x4*)xb, (int)(NELEM / 4));
  k_convert<<<432, 256, 0, stream>>>((const float4*)qkvw, (bf16x4*)wqkv, 3 * DIMC * DIMC / 4);
  k_convert<<<144, 256, 0, stream>>>((const float4*)projw, (bf16x4*)wproj, DIMC * DIMC / 4);
  k_biasT<<<(NHEADS * NTOK * NTOK + 255) / 256, 256, 0, stream>>>(btab, rel, biasT);

  k_gemm<0><<<dim3(1152 / 128, MROWS / 128), 256, 0, stream>>>(xb, wqkv, qkvb, qb, kb, vb, nullptr);
  k_maskT<<<(64 * NTOK * NTOK + 255) / 256, 256, 0, stream>>>(mask, maskT);
  k_attn<<<(NWINB * NHEADS) / 4, 256, 0, stream>>>(qb, kb, vb, biasT, maskT, xb);
  k_gemm<1><<<dim3(384 / 128, MROWS / 128), 256, 0, stream>>>(xb, wproj, projb, nullptr, nullptr, nullptr, out);
}

// Round 5
// 843.265 us; speedup vs baseline: 1.0593x; 1.0267x over previous
//
#include <hip/hip_runtime.h>

typedef __bf16 bf16;
typedef __bf16 bf16x4 __attribute__((ext_vector_type(4)));
typedef __bf16 bf16x8 __attribute__((ext_vector_type(8)));
typedef float f32x4 __attribute__((ext_vector_type(4)));
typedef float f32x16 __attribute__((ext_vector_type(16)));
typedef int i32x2 __attribute__((ext_vector_type(2)));
typedef unsigned int u32;

#define DIMC 384
#define NHEADS 12
#define NTOK 49
#define NWINB 4096
#define MROWS (NWINB*NTOK)   // 200704

#define MFMA32(A,B,C) __builtin_amdgcn_mfma_f32_32x32x16_bf16(A,B,C,0,0,0)

// async global->LDS, 16B per lane; LDS dest is wave-uniform base + lane*16
#define GLOAD16(gsrc, lbase) \
  __builtin_amdgcn_global_load_lds( \
      (const __attribute__((address_space(1))) u32*)(gsrc), \
      (__attribute__((address_space(3))) u32*)(lbase), 16, 0, 0)

// ---------------- convert f32 -> bf16 (vectorized) ----------------
__global__ __launch_bounds__(256) void k_convert(const float4* __restrict__ in,
                                                 bf16x4* __restrict__ out, int n4) {
  int stride = gridDim.x * blockDim.x;
  for (int i = blockIdx.x * blockDim.x + threadIdx.x; i < n4; i += stride) {
    float4 v = in[i];
    bf16x4 o;
    o[0] = (bf16)v.x; o[1] = (bf16)v.y; o[2] = (bf16)v.z; o[3] = (bf16)v.w;
    out[i] = o;
  }
}

// ---------------- transposed bias: biasT[h][key][q] = table[rel[q*49+key]*12 + h] ----------------
__global__ __launch_bounds__(256) void k_biasT(const float* __restrict__ table,
                                               const int* __restrict__ rel,
                                               float* __restrict__ outp) {
  int i = blockIdx.x * 256 + threadIdx.x;
  if (i < NHEADS * NTOK * NTOK) {
    int h = i / (NTOK * NTOK), r2 = i - h * (NTOK * NTOK);
    int key = r2 / NTOK, q = r2 - key * NTOK;
    outp[i] = table[rel[q * NTOK + key] * NHEADS + h];
  }
}

// ---------------- transposed mask: maskT[w][key][q] = mask[w][q][key] ----------------
__global__ __launch_bounds__(256) void k_maskT(const float* __restrict__ mask,
                                               float* __restrict__ outp) {
  int i = blockIdx.x * 256 + threadIdx.x;
  if (i < 64 * NTOK * NTOK) {
    int w = i / (NTOK * NTOK), r2 = i - w * (NTOK * NTOK);
    int key = r2 / NTOK, q = r2 - key * NTOK;
    outp[i] = mask[(w * NTOK + q) * NTOK + key];
  }
}

// ---------------- GEMM: C = A(M,K) * Bw(N,K)^T, bf16 in, f32 acc ----------------
// T3-minimum schedule: double-buffered LDS, prefetch next K-tile via
// global_load_lds BEFORE computing current, counted s_waitcnt vmcnt(8)
// (prefetch loads stay in flight across the barrier), raw s_barrier (no
// __syncthreads -> no vmcnt(0) drain). XOR-swizzled LDS via pre-swizzled
// global source (rule #21). XCD-chunk remap: each XCD owns contiguous
// M-panels -> A fetched once per XCD; B stays L2-resident.
// MODE 0: QKV (N=1152), scatter q/k/v bf16.  MODE 1: proj (N=384), f32 out + bias.
template <int MODE>
__global__ __launch_bounds__(256) void k_gemm(const bf16* __restrict__ A,
                                              const bf16* __restrict__ Bw,
                                              const float* __restrict__ bias,
                                              bf16* __restrict__ oQ, bf16* __restrict__ oK,
                                              bf16* __restrict__ oV, float* __restrict__ oP) {
  __shared__ __align__(16) bf16 lA[2][128 * 64];
  __shared__ __align__(16) bf16 lB[2][128 * 64];
  const int t = threadIdx.x;
  const int l = t & 63;
  const int wv = t >> 6;
  const int wr = wv >> 1, wc = wv & 1;   // 2x2 waves, 64x64 each

  // ---- bijective XCD-chunk remap (nwg % 8 == 0 for both modes) ----
  const u32 NXB = MODE == 0 ? 9 : 3;                 // N-blocks
  const u32 nwg = NXB * (MROWS / 128);
  u32 lin = blockIdx.y * gridDim.x + blockIdx.x;     // dispatch-linear (x fastest)
  u32 logical = (lin & 7) * (nwg >> 3) + (lin >> 3); // XCD gets contiguous chunk
  const int n0 = (int)(logical % NXB) * 128;
  const int m0 = (int)(logical / NXB) * 128;

  const int lr = l & 15, lg = l >> 4;

  // staging geometry: lane's linear tile byte offset = wv*4096 + i*1024 + l*16
  const int srow = wv * 32 + (l >> 3);           // + i*8 per issue
  const int scolb = (l & 7) * 16;                // byte col within 128B row

  f32x4 acc[4][4] = {};

  // per-lane pre-swizzled source column (elements) for each of the 4 issues
  int scolA[4];
#pragma unroll
  for (int i = 0; i < 4; ++i) {
    int row = srow + i * 8;
    scolA[i] = (scolb ^ ((row & 7) << 4)) >> 1;
  }

#define STAGE(BUF, K0)                                                            \
  {                                                                               \
    _Pragma("unroll") for (int i = 0; i < 4; ++i) {                               \
      int row = srow + i * 8;                                                     \
      GLOAD16(&A[(size_t)(m0 + row) * DIMC + (K0) + scolA[i]],                    \
              &lA[BUF][wv * 2048 + i * 512]);                                     \
      GLOAD16(&Bw[(size_t)(n0 + row) * DIMC + (K0) + scolA[i]],                   \
              &lB[BUF][wv * 2048 + i * 512]);                                     \
    }                                                                             \
  }

  STAGE(0, 0);                      // prologue: tile 0 in flight

#pragma unroll
  for (int tt = 0; tt < 6; ++tt) {  // K = 384 = 6 x 64, fully unrolled
    const int cur = tt & 1;
    if (tt > 0) __builtin_amdgcn_s_barrier();      // compute(tt-1) done -> buf reuse safe
    if (tt < 5) {
      STAGE(cur ^ 1, (tt + 1) * 64);               // prefetch next tile
      asm volatile("s_waitcnt vmcnt(8)" ::: "memory");   // wait ONLY tile-tt's 8 loads
    } else {
      asm volatile("s_waitcnt vmcnt(0)" ::: "memory");
    }
    __builtin_amdgcn_s_barrier();                  // all waves' tile-tt data visible

#pragma unroll
    for (int kk = 0; kk < 64; kk += 32) {
      bf16x8 af[4], bfv[4];
#pragma unroll
      for (int f = 0; f < 4; ++f) {
        int row = wr * 64 + f * 16 + lr;
        int cb = (kk + lg * 8) * 2;
        af[f] = *reinterpret_cast<const bf16x8*>(
            &lA[cur][row * 64 + ((cb ^ ((row & 7) << 4)) >> 1)]);
      }
#pragma unroll
      for (int f = 0; f < 4; ++f) {
        int row = wc * 64 + f * 16 + lr;
        int cb = (kk + lg * 8) * 2;
        bfv[f] = *reinterpret_cast<const bf16x8*>(
            &lB[cur][row * 64 + ((cb ^ ((row & 7) << 4)) >> 1)]);
      }
#pragma unroll
      for (int fm = 0; fm < 4; ++fm)
#pragma unroll
        for (int fn = 0; fn < 4; ++fn)
          acc[fm][fn] = __builtin_amdgcn_mfma_f32_16x16x32_bf16(af[fm], bfv[fn], acc[fm][fn], 0, 0, 0);
    }
  }
#undef STAGE

  // epilogue: C/D frag mapping col = lane&15, row = (lane>>4)*4 + r  [m89-verified]
#pragma unroll
  for (int fm = 0; fm < 4; ++fm) {
#pragma unroll
    for (int fn = 0; fn < 4; ++fn) {
      int c = n0 + wc * 64 + fn * 16 + lr;
      float bc = bias[c];
#pragma unroll
      for (int r = 0; r < 4; ++r) {
        int m = m0 + wr * 64 + fm * 16 + lg * 4 + r;
        float v = acc[fm][fn][r] + bc;
        if (MODE == 0) {
          int b = m / 49, n = m - b * 49;
          int which = c / 384;
          int rem = c - which * 384;
          int h = rem >> 5, d = rem & 31;
          bf16* dst = which == 0 ? oQ : (which == 1 ? oK : oV);
          dst[((b * 12 + h) * 49 + n) * 32 + d] = (bf16)v;
        } else {
          oP[m * 384 + c] = v;
        }
      }
    }
  }
}

// ---------------- fused window attention: one wave per (b,h), 32x32 MFMA ----------------
__global__ __launch_bounds__(256, 4) void k_attn(const bf16* __restrict__ Q,
                                                 const bf16* __restrict__ K,
                                                 const bf16* __restrict__ V,
                                                 const float* __restrict__ biasT,
                                                 const float* __restrict__ maskT,
                                                 bf16* __restrict__ H) {
  __shared__ __align__(16) bf16 Vl[4][32 * 72];
  const int t = threadIdx.x, l = t & 63, wv = t >> 6;
  const int p = blockIdx.x * 4 + wv;   // b*12 + h
  const int b = p / 12, h = p - b * 12;
  const int w = b & 63;
  const size_t base = (size_t)p * (49 * 32);
  const int c = l & 31, b5 = l >> 5;
  bf16* vl = Vl[wv];

  {
    bf16x4 z = {};
    for (int i = l; i < 128; i += 64) {
      int d = i >> 2, kq = 48 + (i & 3) * 4;
      *reinterpret_cast<bf16x4*>(&vl[d * 72 + kq]) = z;
    }
  }
  for (int i = l; i < 392; i += 64) {
    int key = i >> 3, dc = (i & 7) * 4;
    bf16x4 vv = *reinterpret_cast<const bf16x4*>(&V[base + key * 32 + dc]);
#pragma unroll
    for (int j = 0; j < 4; ++j) vl[(dc + j) * 72 + key] = vv[j];
  }

  bf16x8 kf[2][2], qf[2][2];
#pragma unroll
  for (int f = 0; f < 2; ++f) {
    int row = f * 32 + c; if (row > 48) row = 48;
#pragma unroll
    for (int kd = 0; kd < 2; ++kd) {
      kf[f][kd] = *reinterpret_cast<const bf16x8*>(&K[base + row * 32 + kd * 16 + b5 * 8]);
      qf[f][kd] = *reinterpret_cast<const bf16x8*>(&Q[base + row * 32 + kd * 16 + b5 * 8]);
    }
  }

  const float scale = 0.17677669529663689f;   // 32^-0.5
  const float* bT = biasT + h * 2401;
  const float* mT = maskT + w * 2401;

#pragma unroll
  for (int fn = 0; fn < 2; ++fn) {
    f32x16 s0 = {}, s1 = {};
    s0 = MFMA32(kf[0][0], qf[fn][0], s0);
    s0 = MFMA32(kf[0][1], qf[fn][1], s0);
    s1 = MFMA32(kf[1][0], qf[fn][0], s1);
    s1 = MFMA32(kf[1][1], qf[fn][1], s1);

    int q = fn * 32 + c;
    int qc = q > 48 ? 48 : q;

    float vals[32];
    float vmax = -1e30f;
#pragma unroll
    for (int fm = 0; fm < 2; ++fm) {
#pragma unroll
      for (int r = 0; r < 16; ++r) {
        int key = fm * 32 + (r & 3) + 8 * (r >> 2) + 4 * b5;
        float sv = fm ? s1[r] : s0[r];
        float v;
        if (key < 49) {
          float cm = bT[key * 49 + qc] + mT[key * 49 + qc];
          v = fmaf(sv, scale, cm);
        } else {
          v = -1e30f;
        }
        vals[fm * 16 + r] = v;
        vmax = fmaxf(vmax, v);
      }
    }
    vmax = fmaxf(vmax, __shfl_xor(vmax, 32));
    float sum = 0.f;
#pragma unroll
    for (int i = 0; i < 32; ++i) {
      float e = __expf(vals[i] - vmax);
      vals[i] = e;
      sum += e;
    }
    sum += __shfl_xor(sum, 32);
    float inv = 1.f / sum;

    f32x16 o = {};
#pragma unroll
    for (int kk = 0; kk < 4; ++kk) {
      int ib = (kk >> 1) * 16 + 8 * (kk & 1);
      union { bf16 hh[2]; u32 u; } cv;
      u32 A0, A1, B0, B1;
      cv.hh[0] = (bf16)(vals[ib + 0] * inv); cv.hh[1] = (bf16)(vals[ib + 1] * inv); A0 = cv.u;
      cv.hh[0] = (bf16)(vals[ib + 2] * inv); cv.hh[1] = (bf16)(vals[ib + 3] * inv); A1 = cv.u;
      cv.hh[0] = (bf16)(vals[ib + 4] * inv); cv.hh[1] = (bf16)(vals[ib + 5] * inv); B0 = cv.u;
      cv.hh[0] = (bf16)(vals[ib + 6] * inv); cv.hh[1] = (bf16)(vals[ib + 7] * inv); B1 = cv.u;
      i32x2 sw0 = __builtin_amdgcn_permlane32_swap((int)A0, (int)B0, false, false);
      i32x2 sw1 = __builtin_amdgcn_permlane32_swap((int)A1, (int)B1, false, false);
      union { u32 d[4]; bf16x8 v8; } pa;
      pa.d[0] = (u32)sw0[0]; pa.d[1] = (u32)sw1[0];
      pa.d[2] = (u32)sw0[1]; pa.d[3] = (u32)sw1[1];
      bf16x8 vf = *reinterpret_cast<const bf16x8*>(&vl[c * 72 + kk * 16 + b5 * 8]);
      o = MFMA32(pa.v8, vf, o);
    }

#pragma unroll
    for (int r = 0; r < 16; ++r) {
      int qrow = fn * 32 + (r & 3) + 8 * (r >> 2) + 4 * b5;
      if (qrow < 49)
        H[((size_t)b * 49 + qrow) * 384 + h * 32 + c] = (bf16)o[r];
    }
  }
}

extern "C" void kernel_launch(void* const* d_in, const int* in_sizes, int n_in,
                              void* d_out, int out_size, void* d_ws, size_t ws_size,
                              hipStream_t stream) {
  const float* x     = (const float*)d_in[0];
  const float* mask  = (const float*)d_in[1];
  const float* qkvw  = (const float*)d_in[2];
  const float* qkvb  = (const float*)d_in[3];
  const float* btab  = (const float*)d_in[4];
  const float* projw = (const float*)d_in[5];
  const float* projb = (const float*)d_in[6];
  const int*   rel   = (const int*)d_in[7];
  float* out = (float*)d_out;

  const size_t NELEM = (size_t)MROWS * DIMC;  // 77,070,336
  char* ws = (char*)d_ws;
  // ws layout (bytes):
  //   xb/hidden [0, 154140672)
  //   v         [154140672, 308281344)
  //   biasT     [308281344, +115456)
  //   wqkv      [308396800, +884736)   <- maskT (614656 B) reuses this AFTER gemm0
  //   wproj     [309281536, +294912)
  bf16*  xb    = (bf16*)ws;
  bf16*  vb    = (bf16*)(ws + 154140672);
  float* biasT = (float*)(ws + 308281344);
  bf16*  wqkv  = (bf16*)(ws + 308396800);
  float* maskT = (float*)(ws + 308396800);   // aliases wqkv; written after gemm0
  bf16*  wproj = (bf16*)(ws + 309281536);
  // q,k live in d_out as scratch (exactly 2 * 154,140,672 B); proj fully overwrites it
  bf16* qb = (bf16*)d_out;
  bf16* kb = qb + NELEM;

  k_convert<<<2048, 256, 0, stream>>>((const float4*)x, (bf16x4*)xb, (int)(NELEM / 4));
  k_convert<<<432, 256, 0, stream>>>((const float4*)qkvw, (bf16x4*)wqkv, 3 * DIMC * DIMC / 4);
  k_convert<<<144, 256, 0, stream>>>((const float4*)projw, (bf16x4*)wproj, DIMC * DIMC / 4);
  k_biasT<<<(NHEADS * NTOK * NTOK + 255) / 256, 256, 0, stream>>>(btab, rel, biasT);

  k_gemm<0><<<dim3(1152 / 128, MROWS / 128), 256, 0, stream>>>(xb, wqkv, qkvb, qb, kb, vb, nullptr);
  k_maskT<<<(64 * NTOK * NTOK + 255) / 256, 256, 0, stream>>>(mask, maskT);
  k_attn<<<(NWINB * NHEADS) / 4, 256, 0, stream>>>(qb, kb, vb, biasT, maskT, xb);
  k_gemm<1><<<dim3(384 / 128, MROWS / 128), 256, 0, stream>>>(xb, wproj, projb, nullptr, nullptr, nullptr, out);
}